// Round 16
// baseline (104.027 us; speedup 1.0000x reference)
//
#include <hip/hip_runtime.h>
#include <hip/hip_bf16.h>

#define N_NODES 100000
#define IN_F    128
#define OUT_F   64
#define INV_KEEP (1.0f / 0.9f)

#define RPB_LOG 7                 // rows per bucket = 128
#define RPB (1 << RPB_LOG)
#define NB  ((N_NODES + RPB - 1) / RPB)   // 782 buckets
#define BIN_CHUNK 4096
#define BIN_BS 1024
#define ACC_BS 1024
#define ACC_CHUNK 2560            // edges sorted per pass (avg bucket = 2046)

typedef __attribute__((ext_vector_type(8))) short bf16x8;
typedef __attribute__((ext_vector_type(4))) float f32x4;

__device__ __forceinline__ unsigned bf16rne(float f) {
  unsigned u = __float_as_uint(f);
  u += 0x7FFFu + ((u >> 16) & 1u);
  return u >> 16;
}

// ---------------------------------------------------------------------------
// Kernel 0: W [128][64] f32 -> Wt [64][128] bf16 (one block, runs once/call)
// ---------------------------------------------------------------------------
__global__ __launch_bounds__(256) void wtrans_kernel(
    const float* __restrict__ w, ushort* __restrict__ wt) {
  __shared__ float wsl[IN_F][OUT_F + 1];   // 128x65 f32, padded
  const int t = threadIdx.x;
  #pragma unroll
  for (int i = 0; i < 8; ++i) {
    const int fi = t + i * 256;            // float4 index
    const float4 v = ((const float4*)w)[fi];
    const int fl = 4 * fi;
    const int k = fl >> 6;
    const int c = fl & 63;
    wsl[k][c] = v.x; wsl[k][c + 1] = v.y; wsl[k][c + 2] = v.z; wsl[k][c + 3] = v.w;
  }
  __syncthreads();
  const int c = t >> 2;
  const int k0 = (t & 3) * 32;
  unsigned hw[16];
  #pragma unroll
  for (int i = 0; i < 16; ++i) {
    const unsigned u0 = bf16rne(wsl[k0 + 2 * i][c]);
    const unsigned u1 = bf16rne(wsl[k0 + 2 * i + 1][c]);
    hw[i] = u0 | (u1 << 16);               // low ushort = even k
  }
  uint4* dst = (uint4*)(wt + (size_t)c * IN_F + k0);
  dst[0] = make_uint4(hw[0], hw[1], hw[2], hw[3]);
  dst[1] = make_uint4(hw[4], hw[5], hw[6], hw[7]);
  dst[2] = make_uint4(hw[8], hw[9], hw[10], hw[11]);
  dst[3] = make_uint4(hw[12], hw[13], hw[14], hw[15]);
}

// ---------------------------------------------------------------------------
// Kernel 1: hidden = dropout(x @ W + b) -> bf16, via MFMA 16x16x32 bf16.
// Wave computes 16 rows x 64 cols; x split hi/lo bf16 (2 MFMA) for accuracy.
// R16: ALL 8 x-loads hoisted into one prefetch block (one latency exposure
// instead of 4 serialized load->convert->MFMA rounds).
// Block 0 additionally zeroes cnt[] (replaces a separate memset dispatch).
// ---------------------------------------------------------------------------
__global__ __launch_bounds__(256) void gemm_dropout_kernel(
    const float* __restrict__ x, const ushort* __restrict__ wt,
    const float* __restrict__ bias, const void* __restrict__ mask,
    ushort* __restrict__ hidden, int* __restrict__ cnt) {
  __shared__ float tileT[64][68];          // 17.4 KB, 68-pad -> 2-way banks
  __shared__ int mask_is_u8;

  const int tid = threadIdx.x;
  const int wv = tid >> 6;                 // 0..3
  const int l = tid & 63;
  const int rowbase = blockIdx.x * 64;

  // fused: zero the bucket-histogram counters (hist runs after this kernel)
  if (blockIdx.x == 0 && tid < 196)
    ((int4*)cnt)[tid] = make_int4(0, 0, 0, 0);   // 784 ints >= NB, pad-safe

  if (tid < 64) {
    const unsigned char* m8 = (const unsigned char*)mask;
    unsigned long long b = __ballot(m8[tid] != 0);
    if (tid == 0) mask_is_u8 = (__popcll(b) > 32) ? 1 : 0;
  }

  const int col = l & 15;
  const int kg = l >> 4;                   // 0..3

  int arow = rowbase + 16 * wv + col;
  if (arow >= N_NODES) arow = N_NODES - 1;
  const float* xrow = x + (size_t)arow * IN_F;

  // prefetch ALL x data first (8 independent loads in flight)
  float4 xa[4], xb[4];
  #pragma unroll
  for (int s = 0; s < 4; ++s) {
    xa[s] = *(const float4*)(xrow + 32 * s + 8 * kg);
    xb[s] = *(const float4*)(xrow + 32 * s + 8 * kg + 4);
  }

  // B fragments from Wt (16 KB, L2-resident; same for all blocks)
  bf16x8 bfr[4][4];                        // [col-tile][k-step]
  #pragma unroll
  for (int c = 0; c < 4; ++c)
    #pragma unroll
    for (int s = 0; s < 4; ++s)
      bfr[c][s] =
          *(const bf16x8*)(wt + (size_t)(16 * c + col) * IN_F + 32 * s + 8 * kg);

  f32x4 acc0 = {0.f, 0.f, 0.f, 0.f};
  f32x4 acc1 = {0.f, 0.f, 0.f, 0.f};
  f32x4 acc2 = {0.f, 0.f, 0.f, 0.f};
  f32x4 acc3 = {0.f, 0.f, 0.f, 0.f};

  #pragma unroll
  for (int s = 0; s < 4; ++s) {
    const float f[8] = {xa[s].x, xa[s].y, xa[s].z, xa[s].w,
                        xb[s].x, xb[s].y, xb[s].z, xb[s].w};
    bf16x8 ahi, alo;
    #pragma unroll
    for (int j = 0; j < 8; ++j) {
      const unsigned h = bf16rne(f[j]);
      ahi[j] = (short)h;
      const float lo = f[j] - __uint_as_float(h << 16);
      alo[j] = (short)bf16rne(lo);
    }
    acc0 = __builtin_amdgcn_mfma_f32_16x16x32_bf16(ahi, bfr[0][s], acc0, 0, 0, 0);
    acc1 = __builtin_amdgcn_mfma_f32_16x16x32_bf16(ahi, bfr[1][s], acc1, 0, 0, 0);
    acc2 = __builtin_amdgcn_mfma_f32_16x16x32_bf16(ahi, bfr[2][s], acc2, 0, 0, 0);
    acc3 = __builtin_amdgcn_mfma_f32_16x16x32_bf16(ahi, bfr[3][s], acc3, 0, 0, 0);
    acc0 = __builtin_amdgcn_mfma_f32_16x16x32_bf16(alo, bfr[0][s], acc0, 0, 0, 0);
    acc1 = __builtin_amdgcn_mfma_f32_16x16x32_bf16(alo, bfr[1][s], acc1, 0, 0, 0);
    acc2 = __builtin_amdgcn_mfma_f32_16x16x32_bf16(alo, bfr[2][s], acc2, 0, 0, 0);
    acc3 = __builtin_amdgcn_mfma_f32_16x16x32_bf16(alo, bfr[3][s], acc3, 0, 0, 0);
  }

  #pragma unroll
  for (int r = 0; r < 4; ++r) {
    const int lr = 16 * wv + 4 * kg + r;
    tileT[lr][0 + col]  = acc0[r];
    tileT[lr][16 + col] = acc1[r];
    tileT[lr][32 + col] = acc2[r];
    tileT[lr][48 + col] = acc3[r];
  }
  __syncthreads();

  const unsigned char* m8 = (const unsigned char*)mask;
  const int* m32 = (const int*)mask;
  const int u8mode = mask_is_u8;

  #pragma unroll
  for (int i = 0; i < 2; ++i) {
    const int item = tid + i * 256;
    const int r2 = item >> 3;              // 0..63
    const int cq = (item & 7) * 8;         // 0..56
    const int grow = rowbase + r2;
    if (grow < N_NODES) {
      const float4 b0 = *(const float4*)&bias[cq];
      const float4 b1 = *(const float4*)&bias[cq + 4];
      const float4 v0 = *(const float4*)&tileT[r2][cq];
      const float4 v1 = *(const float4*)&tileT[r2][cq + 4];
      const float vals[8] = {v0.x + b0.x, v0.y + b0.y, v0.z + b0.z, v0.w + b0.w,
                             v1.x + b1.x, v1.y + b1.y, v1.z + b1.z, v1.w + b1.w};
      unsigned keep[8];
      const size_t mbase = (size_t)grow * OUT_F + cq;
      if (u8mode) {
        const uint2 mv = *(const uint2*)(m8 + mbase);
        #pragma unroll
        for (int b = 0; b < 4; ++b) {
          keep[0 + b] = (mv.x >> (8 * b)) & 255u;
          keep[4 + b] = (mv.y >> (8 * b)) & 255u;
        }
      } else {
        const int4 mv0 = *(const int4*)(m32 + mbase);
        const int4 mv1 = *(const int4*)(m32 + mbase + 4);
        keep[0] = (unsigned)mv0.x; keep[1] = (unsigned)mv0.y;
        keep[2] = (unsigned)mv0.z; keep[3] = (unsigned)mv0.w;
        keep[4] = (unsigned)mv1.x; keep[5] = (unsigned)mv1.y;
        keep[6] = (unsigned)mv1.z; keep[7] = (unsigned)mv1.w;
      }
      unsigned hw[4];
      #pragma unroll
      for (int p = 0; p < 4; ++p) {
        const float w0 = keep[2 * p]     ? vals[2 * p] * INV_KEEP     : 0.f;
        const float w1 = keep[2 * p + 1] ? vals[2 * p + 1] * INV_KEEP : 0.f;
        hw[p] = bf16rne(w0) | (bf16rne(w1) << 16);
      }
      *(uint4*)&hidden[mbase] = make_uint4(hw[0], hw[1], hw[2], hw[3]);
    }
  }
}

// ---------------------------------------------------------------------------
// Kernel 2: bucket histogram (LDS-staged)
// ---------------------------------------------------------------------------
__global__ __launch_bounds__(256) void hist_kernel(
    const int* __restrict__ row_idx, int* __restrict__ cnt, int nedges) {
  __shared__ int hc[NB];
  const int t = threadIdx.x;
  for (int i = t; i < NB; i += 256) hc[i] = 0;
  __syncthreads();
  const int stride = gridDim.x * 256;
  for (int e = blockIdx.x * 256 + t; e < nedges; e += stride)
    atomicAdd(&hc[row_idx[e] >> RPB_LOG], 1);
  __syncthreads();
  for (int i = t; i < NB; i += 256)
    if (hc[i]) atomicAdd(&cnt[i], hc[i]);
}

// ---------------------------------------------------------------------------
// Kernel 3: one-block scan of NB counts -> base[NB+1], cursor[NB]
// ---------------------------------------------------------------------------
__global__ __launch_bounds__(1024) void scan_kernel(
    const int* __restrict__ cnt, int* __restrict__ base,
    int* __restrict__ cursor) {
  __shared__ int s[1024];
  const int t = threadIdx.x;
  const int v = (t < NB) ? cnt[t] : 0;
  s[t] = v;
  __syncthreads();
  int a = v;
  #pragma unroll
  for (int d = 1; d < 1024; d <<= 1) {
    const int add = (t >= d) ? s[t - d] : 0;
    __syncthreads();
    a += add;
    s[t] = a;
    __syncthreads();
  }
  if (t < NB) {
    base[t] = a - v;
    cursor[t] = a - v;
  }
  if (t == NB - 1) base[NB] = a;
}

// ---------------------------------------------------------------------------
// Kernel 4: bin — LDS counting-sort a 4096-edge chunk by bucket, then write
// coalesced runs into each bucket's reserved global range.
// ---------------------------------------------------------------------------
__global__ __launch_bounds__(BIN_BS) void bin_kernel(
    const int* __restrict__ row_idx, const int* __restrict__ col_idx,
    const float* __restrict__ adj, int* __restrict__ cursor,
    int2* __restrict__ packed, int nedges) {
  __shared__ unsigned sMeta[BIN_CHUNK];   // 16 KB
  __shared__ float    sAdj[BIN_CHUNK];    // 16 KB
  __shared__ ushort   sBkt[BIN_CHUNK];    //  8 KB
  __shared__ int      sCnt[1024];         //  4 KB
  __shared__ int      sScan[1024];        //  4 KB
  __shared__ int      sBase[1024];        //  4 KB
  __shared__ int      sFill[1024];        //  4 KB

  const int t = threadIdx.x;
  const int e0 = blockIdx.x * BIN_CHUNK;
  const int n = min(BIN_CHUNK, nedges - e0);

  sCnt[t] = 0;
  sBase[t] = 0;
  sFill[t] = 0;
  __syncthreads();

  int      eb[4];
  unsigned em[4];
  float    ea[4];
  #pragma unroll
  for (int j = 0; j < 4; ++j) {
    const int idx = t + j * BIN_BS;
    eb[j] = -1;
    if (idx < n) {
      const int r = row_idx[e0 + idx];
      const int c = col_idx[e0 + idx];
      ea[j] = adj[e0 + idx];
      eb[j] = r >> RPB_LOG;
      em[j] = ((unsigned)(r & (RPB - 1)) << 17) | (unsigned)c;
      atomicAdd(&sCnt[eb[j]], 1);
    }
  }
  __syncthreads();

  const int v = sCnt[t];
  sScan[t] = v;
  __syncthreads();
  int a = v;
  #pragma unroll
  for (int d = 1; d < 1024; d <<= 1) {
    const int add = (t >= d) ? sScan[t - d] : 0;
    __syncthreads();
    a += add;
    sScan[t] = a;
    __syncthreads();
  }
  const int excl = a - v;
  sScan[t] = excl;
  if (v > 0 && t < NB) sBase[t] = atomicAdd(&cursor[t], v);
  __syncthreads();

  #pragma unroll
  for (int j = 0; j < 4; ++j) {
    if (eb[j] >= 0) {
      const int p = sScan[eb[j]] + atomicAdd(&sFill[eb[j]], 1);
      sMeta[p] = em[j];
      sAdj[p] = ea[j];
      sBkt[p] = (ushort)eb[j];
    }
  }
  __syncthreads();

  #pragma unroll
  for (int j = 0; j < 4; ++j) {
    const int sp = t + j * BIN_BS;
    if (sp < n) {
      const int b = sBkt[sp];
      const int dst = sBase[b] + (sp - sScan[b]);
      int2 o;
      o.x = (int)sMeta[sp];
      o.y = __float_as_int(sAdj[sp]);
      packed[dst] = o;
    }
  }
}

// ---------------------------------------------------------------------------
// Kernel 5: bucket accumulate. Dual-row half-wave split (proven R15): lane =
// (h=lane>>5 row-selector, q=(lane>>4)&1 edge-parity, fl=lane&15 feat-quad).
// One global_load_dwordx2 serves 4 edges across 2 independent rows.
// ---------------------------------------------------------------------------
__global__ __launch_bounds__(ACC_BS) void bucket_acc_kernel(
    const int* __restrict__ base, const int2* __restrict__ packed,
    const ushort* __restrict__ hidden, float* __restrict__ out) {
  __shared__ float accT[RPB * OUT_F];    // 32 KB
  __shared__ int2  sEdge[ACC_CHUNK];     // 20 KB (meta, adj-bits)
  __shared__ int   rowCnt[RPB];
  __shared__ int   rowOff[RPB + 1];
  __shared__ int   sTmp[RPB];

  const int t = threadIdx.x;
  const int b = blockIdx.x;
  const int lane = t & 63;
  const int h  = lane >> 5;        // row-in-pair selector 0/1
  const int q  = (lane >> 4) & 1;  // edge parity within row
  const int fl = lane & 15;        // feat-quad index (feats 4fl..4fl+3)
  const int wv = t >> 6;           // 0..15

  const uint2* __restrict__ hid64 = (const uint2*)hidden; // [node][16]

  float4* a4 = (float4*)accT;
  #pragma unroll
  for (int i = 0; i < 2; ++i)
    a4[t + i * ACC_BS] = make_float4(0.f, 0.f, 0.f, 0.f);

  const int s = base[b];
  const int e = base[b + 1];

  for (int g0 = s; g0 < e; g0 += ACC_CHUNK) {
    const int n = min(ACC_CHUNK, e - g0);

    if (t < RPB) rowCnt[t] = 0;
    __syncthreads();

    // load up to 3 edges/thread (coalesced), count rows (int LDS atomics)
    int2 ev[3];
    int  ro[3], pos[3];
    #pragma unroll
    for (int j = 0; j < 3; ++j) {
      const int idx = t + j * ACC_BS;
      ro[j] = -1;
      if (idx < n) {
        ev[j] = packed[g0 + idx];
        ro[j] = (int)(((unsigned)ev[j].x >> 17) & (RPB - 1));
        pos[j] = atomicAdd(&rowCnt[ro[j]], 1);
      }
    }
    __syncthreads();

    // block-wide exclusive scan of 128 row counts (proven)
    if (t < RPB) sTmp[t] = rowCnt[t];
    __syncthreads();
    for (int d = 1; d < RPB; d <<= 1) {
      int add = 0;
      if (t < RPB && t >= d) add = sTmp[t - d];
      __syncthreads();
      if (t < RPB) sTmp[t] += add;
      __syncthreads();
    }
    if (t < RPB) rowOff[t] = sTmp[t] - rowCnt[t];
    if (t == 0) rowOff[RPB] = n;
    __syncthreads();

    // scatter into row-sorted LDS positions (1 ds_write_b64 per edge)
    #pragma unroll
    for (int j = 0; j < 3; ++j) {
      if (ro[j] >= 0) sEdge[rowOff[ro[j]] + pos[j]] = ev[j];
    }
    __syncthreads();

    // accumulate: wave wv owns rows wv*8..wv*8+7 as 4 pairs; half-wave h
    // owns row 2*pr+h of each pair -> 2 independent gather chains per wave
    for (int pr = 0; pr < 4; ++pr) {
      const int r = wv * 8 + 2 * pr + h;
      const int rs = rowOff[r];
      const int re = rowOff[r + 1];
      float acc0 = 0.f, acc1 = 0.f, acc2 = 0.f, acc3 = 0.f;
      int i = rs + q;                 // this lane's edge stream: rs+q, +2, ...
      while (__any(i < re)) {
        const bool v0 = i < re;
        const bool v1 = i + 2 < re;
        const int2 e0 = sEdge[v0 ? i : 0];
        const int2 e1 = sEdge[v1 ? i + 2 : 0];
        const uint2 g0v = hid64[((unsigned)e0.x & 0x1FFFFu) * 16 + fl];
        const uint2 g1v = hid64[((unsigned)e1.x & 0x1FFFFu) * 16 + fl];
        const float a0 = v0 ? __int_as_float(e0.y) : 0.f;
        const float a1 = v1 ? __int_as_float(e1.y) : 0.f;
        acc0 = fmaf(a0, __uint_as_float(g0v.x << 16), acc0);
        acc1 = fmaf(a0, __uint_as_float(g0v.x & 0xFFFF0000u), acc1);
        acc2 = fmaf(a0, __uint_as_float(g0v.y << 16), acc2);
        acc3 = fmaf(a0, __uint_as_float(g0v.y & 0xFFFF0000u), acc3);
        acc0 = fmaf(a1, __uint_as_float(g1v.x << 16), acc0);
        acc1 = fmaf(a1, __uint_as_float(g1v.x & 0xFFFF0000u), acc1);
        acc2 = fmaf(a1, __uint_as_float(g1v.y << 16), acc2);
        acc3 = fmaf(a1, __uint_as_float(g1v.y & 0xFFFF0000u), acc3);
        i += 4;
      }
      // combine the two parities within this half (lane^16 flips q)
      acc0 += __shfl_xor(acc0, 16);
      acc1 += __shfl_xor(acc1, 16);
      acc2 += __shfl_xor(acc2, 16);
      acc3 += __shfl_xor(acc3, 16);
      if (q == 0) {
        float4* dst = (float4*)&accT[r * OUT_F + 4 * fl];
        float4 v = *dst;
        v.x += acc0; v.y += acc1; v.z += acc2; v.w += acc3;
        *dst = v;
      }
    }
    __syncthreads();  // chunk done before rowCnt/sEdge reuse
  }

  __syncthreads();
  const int rbase = b * RPB;
  float4* o4 = (float4*)(out + (size_t)rbase * OUT_F);
  #pragma unroll
  for (int i = 0; i < 2; ++i) {
    const int idx4 = t + i * ACC_BS;
    const int r = idx4 >> 4;  // 16 float4 per row
    if (rbase + r < N_NODES) {
      float4 vv = a4[idx4];
      vv.x = fmaxf(vv.x, 0.f);
      vv.y = fmaxf(vv.y, 0.f);
      vv.z = fmaxf(vv.z, 0.f);
      vv.w = fmaxf(vv.w, 0.f);
      o4[idx4] = vv;
    }
  }
}

extern "C" void kernel_launch(void* const* d_in, const int* in_sizes, int n_in,
                              void* d_out, int out_size, void* d_ws,
                              size_t ws_size, hipStream_t stream) {
  const float* x       = (const float*)d_in[0];
  const int*   row_idx = (const int*)d_in[1];
  const int*   col_idx = (const int*)d_in[2];
  const float* adj     = (const float*)d_in[3];
  const void*  mask    = d_in[4];
  const float* w       = (const float*)d_in[5];
  const float* bias    = (const float*)d_in[6];
  float* out = (float*)d_out;
  const int nedges = in_sizes[1];

  // ws layout (16B-aligned): hidden bf16 | cnt | base | cursor | packed | Wt
  char* ws = (char*)d_ws;
  const size_t off_hidden = 0;
  const size_t sz_hidden  = (size_t)N_NODES * OUT_F * sizeof(ushort);  // 12.8MB
  const size_t off_cnt    = (off_hidden + sz_hidden + 15) & ~(size_t)15;
  const size_t off_base   = (off_cnt + NB * 4 + 15) & ~(size_t)15;
  const size_t off_cursor = (off_base + (NB + 1) * 4 + 15) & ~(size_t)15;
  const size_t off_packed = (off_cursor + NB * 4 + 15) & ~(size_t)15;
  const size_t off_wt     = (off_packed + (size_t)nedges * 8 + 15) & ~(size_t)15;

  ushort* hidden = (ushort*)(ws + off_hidden);
  int*    cnt    = (int*)(ws + off_cnt);
  int*    base   = (int*)(ws + off_base);
  int*    cursor = (int*)(ws + off_cursor);
  int2*   packed = (int2*)(ws + off_packed);
  ushort* wt     = (ushort*)(ws + off_wt);

  wtrans_kernel<<<1, 256, 0, stream>>>(w, wt);
  gemm_dropout_kernel<<<(N_NODES + 63) / 64, 256, 0, stream>>>(
      x, wt, bias, mask, hidden, cnt);

  hist_kernel<<<512, 256, 0, stream>>>(row_idx, cnt, nedges);
  scan_kernel<<<1, 1024, 0, stream>>>(cnt, base, cursor);
  bin_kernel<<<(nedges + BIN_CHUNK - 1) / BIN_CHUNK, BIN_BS, 0, stream>>>(
      row_idx, col_idx, adj, cursor, packed, nedges);
  bucket_acc_kernel<<<NB, ACC_BS, 0, stream>>>(base, packed, hidden, out);
}

// Round 17
// 87.635 us; speedup vs baseline: 1.1871x; 1.1871x over previous
//
#include <hip/hip_runtime.h>
#include <hip/hip_bf16.h>

#define N_NODES 100000
#define IN_F    128
#define OUT_F   64
#define INV_KEEP (1.0f / 0.9f)

#define RPB_LOG 7                 // rows per bucket = 128
#define RPB (1 << RPB_LOG)
#define NB  ((N_NODES + RPB - 1) / RPB)   // 782 buckets
#define CAP 3072                  // fixed slab per bucket (mean 2048, +22 sigma)
#define BIN_CHUNK 4096
#define BIN_BS 1024
#define ACC_BS 1024
#define ACC_CHUNK 2560            // edges sorted per pass (avg bucket = 2046)

typedef __attribute__((ext_vector_type(8))) short bf16x8;
typedef __attribute__((ext_vector_type(4))) float f32x4;

__device__ __forceinline__ unsigned bf16rne(float f) {
  unsigned u = __float_as_uint(f);
  u += 0x7FFFu + ((u >> 16) & 1u);
  return u >> 16;
}

// ---------------------------------------------------------------------------
// Kernel 0: W [128][64] f32 -> Wt [64][128] bf16 (one block, runs once/call)
// ---------------------------------------------------------------------------
__global__ __launch_bounds__(256) void wtrans_kernel(
    const float* __restrict__ w, ushort* __restrict__ wt) {
  __shared__ float wsl[IN_F][OUT_F + 1];   // 128x65 f32, padded
  const int t = threadIdx.x;
  #pragma unroll
  for (int i = 0; i < 8; ++i) {
    const int fi = t + i * 256;            // float4 index
    const float4 v = ((const float4*)w)[fi];
    const int fl = 4 * fi;
    const int k = fl >> 6;
    const int c = fl & 63;
    wsl[k][c] = v.x; wsl[k][c + 1] = v.y; wsl[k][c + 2] = v.z; wsl[k][c + 3] = v.w;
  }
  __syncthreads();
  const int c = t >> 2;
  const int k0 = (t & 3) * 32;
  unsigned hw[16];
  #pragma unroll
  for (int i = 0; i < 16; ++i) {
    const unsigned u0 = bf16rne(wsl[k0 + 2 * i][c]);
    const unsigned u1 = bf16rne(wsl[k0 + 2 * i + 1][c]);
    hw[i] = u0 | (u1 << 16);               // low ushort = even k
  }
  uint4* dst = (uint4*)(wt + (size_t)c * IN_F + k0);
  dst[0] = make_uint4(hw[0], hw[1], hw[2], hw[3]);
  dst[1] = make_uint4(hw[4], hw[5], hw[6], hw[7]);
  dst[2] = make_uint4(hw[8], hw[9], hw[10], hw[11]);
  dst[3] = make_uint4(hw[12], hw[13], hw[14], hw[15]);
}

// ---------------------------------------------------------------------------
// Kernel 1: hidden = dropout(x @ W + b) -> bf16, via MFMA 16x16x32 bf16.
// Wave computes 16 rows x 64 cols; x split hi/lo bf16 (2 MFMA) for accuracy.
// Block 0 additionally initializes cursor[b] = b*CAP (slab bases; replaces
// the hist+scan pipeline entirely).
// ---------------------------------------------------------------------------
__global__ __launch_bounds__(256) void gemm_dropout_kernel(
    const float* __restrict__ x, const ushort* __restrict__ wt,
    const float* __restrict__ bias, const void* __restrict__ mask,
    ushort* __restrict__ hidden, int* __restrict__ cursor) {
  __shared__ float tileT[64][68];          // 17.4 KB, 68-pad -> 2-way banks
  __shared__ int mask_is_u8;

  const int tid = threadIdx.x;
  const int wv = tid >> 6;                 // 0..3
  const int l = tid & 63;
  const int rowbase = blockIdx.x * 64;

  // fused: init per-bucket slab cursors (bin reserves from these)
  if (blockIdx.x == 0 && tid < 196) {
    const int c0 = 4 * tid;
    ((int4*)cursor)[tid] =
        make_int4(c0 * CAP, (c0 + 1) * CAP, (c0 + 2) * CAP, (c0 + 3) * CAP);
  }

  if (tid < 64) {
    const unsigned char* m8 = (const unsigned char*)mask;
    unsigned long long b = __ballot(m8[tid] != 0);
    if (tid == 0) mask_is_u8 = (__popcll(b) > 32) ? 1 : 0;
  }

  const int col = l & 15;
  const int kg = l >> 4;                   // 0..3

  int arow = rowbase + 16 * wv + col;
  if (arow >= N_NODES) arow = N_NODES - 1;
  const float* xrow = x + (size_t)arow * IN_F;

  // prefetch ALL x data first (8 independent loads in flight)
  float4 xa[4], xb[4];
  #pragma unroll
  for (int s = 0; s < 4; ++s) {
    xa[s] = *(const float4*)(xrow + 32 * s + 8 * kg);
    xb[s] = *(const float4*)(xrow + 32 * s + 8 * kg + 4);
  }

  // B fragments from Wt (16 KB, L2-resident; same for all blocks)
  bf16x8 bfr[4][4];                        // [col-tile][k-step]
  #pragma unroll
  for (int c = 0; c < 4; ++c)
    #pragma unroll
    for (int s = 0; s < 4; ++s)
      bfr[c][s] =
          *(const bf16x8*)(wt + (size_t)(16 * c + col) * IN_F + 32 * s + 8 * kg);

  f32x4 acc0 = {0.f, 0.f, 0.f, 0.f};
  f32x4 acc1 = {0.f, 0.f, 0.f, 0.f};
  f32x4 acc2 = {0.f, 0.f, 0.f, 0.f};
  f32x4 acc3 = {0.f, 0.f, 0.f, 0.f};

  #pragma unroll
  for (int s = 0; s < 4; ++s) {
    const float f[8] = {xa[s].x, xa[s].y, xa[s].z, xa[s].w,
                        xb[s].x, xb[s].y, xb[s].z, xb[s].w};
    bf16x8 ahi, alo;
    #pragma unroll
    for (int j = 0; j < 8; ++j) {
      const unsigned h = bf16rne(f[j]);
      ahi[j] = (short)h;
      const float lo = f[j] - __uint_as_float(h << 16);
      alo[j] = (short)bf16rne(lo);
    }
    acc0 = __builtin_amdgcn_mfma_f32_16x16x32_bf16(ahi, bfr[0][s], acc0, 0, 0, 0);
    acc1 = __builtin_amdgcn_mfma_f32_16x16x32_bf16(ahi, bfr[1][s], acc1, 0, 0, 0);
    acc2 = __builtin_amdgcn_mfma_f32_16x16x32_bf16(ahi, bfr[2][s], acc2, 0, 0, 0);
    acc3 = __builtin_amdgcn_mfma_f32_16x16x32_bf16(ahi, bfr[3][s], acc3, 0, 0, 0);
    acc0 = __builtin_amdgcn_mfma_f32_16x16x32_bf16(alo, bfr[0][s], acc0, 0, 0, 0);
    acc1 = __builtin_amdgcn_mfma_f32_16x16x32_bf16(alo, bfr[1][s], acc1, 0, 0, 0);
    acc2 = __builtin_amdgcn_mfma_f32_16x16x32_bf16(alo, bfr[2][s], acc2, 0, 0, 0);
    acc3 = __builtin_amdgcn_mfma_f32_16x16x32_bf16(alo, bfr[3][s], acc3, 0, 0, 0);
  }

  #pragma unroll
  for (int r = 0; r < 4; ++r) {
    const int lr = 16 * wv + 4 * kg + r;
    tileT[lr][0 + col]  = acc0[r];
    tileT[lr][16 + col] = acc1[r];
    tileT[lr][32 + col] = acc2[r];
    tileT[lr][48 + col] = acc3[r];
  }
  __syncthreads();

  const unsigned char* m8 = (const unsigned char*)mask;
  const int* m32 = (const int*)mask;
  const int u8mode = mask_is_u8;

  #pragma unroll
  for (int i = 0; i < 2; ++i) {
    const int item = tid + i * 256;
    const int r2 = item >> 3;              // 0..63
    const int cq = (item & 7) * 8;         // 0..56
    const int grow = rowbase + r2;
    if (grow < N_NODES) {
      const float4 b0 = *(const float4*)&bias[cq];
      const float4 b1 = *(const float4*)&bias[cq + 4];
      const float4 v0 = *(const float4*)&tileT[r2][cq];
      const float4 v1 = *(const float4*)&tileT[r2][cq + 4];
      const float vals[8] = {v0.x + b0.x, v0.y + b0.y, v0.z + b0.z, v0.w + b0.w,
                             v1.x + b1.x, v1.y + b1.y, v1.z + b1.z, v1.w + b1.w};
      unsigned keep[8];
      const size_t mbase = (size_t)grow * OUT_F + cq;
      if (u8mode) {
        const uint2 mv = *(const uint2*)(m8 + mbase);
        #pragma unroll
        for (int b = 0; b < 4; ++b) {
          keep[0 + b] = (mv.x >> (8 * b)) & 255u;
          keep[4 + b] = (mv.y >> (8 * b)) & 255u;
        }
      } else {
        const int4 mv0 = *(const int4*)(m32 + mbase);
        const int4 mv1 = *(const int4*)(m32 + mbase + 4);
        keep[0] = (unsigned)mv0.x; keep[1] = (unsigned)mv0.y;
        keep[2] = (unsigned)mv0.z; keep[3] = (unsigned)mv0.w;
        keep[4] = (unsigned)mv1.x; keep[5] = (unsigned)mv1.y;
        keep[6] = (unsigned)mv1.z; keep[7] = (unsigned)mv1.w;
      }
      unsigned hw[4];
      #pragma unroll
      for (int p = 0; p < 4; ++p) {
        const float w0 = keep[2 * p]     ? vals[2 * p] * INV_KEEP     : 0.f;
        const float w1 = keep[2 * p + 1] ? vals[2 * p + 1] * INV_KEEP : 0.f;
        hw[p] = bf16rne(w0) | (bf16rne(w1) << 16);
      }
      *(uint4*)&hidden[mbase] = make_uint4(hw[0], hw[1], hw[2], hw[3]);
    }
  }
}

// ---------------------------------------------------------------------------
// Kernel 4: bin — LDS counting-sort a 4096-edge chunk by bucket, then write
// coalesced runs into each bucket's FIXED SLAB (cursor[b] starts at b*CAP;
// per-block atomicAdd reservation). No hist/scan needed.
// ---------------------------------------------------------------------------
__global__ __launch_bounds__(BIN_BS) void bin_kernel(
    const int* __restrict__ row_idx, const int* __restrict__ col_idx,
    const float* __restrict__ adj, int* __restrict__ cursor,
    int2* __restrict__ packed, int nedges) {
  __shared__ unsigned sMeta[BIN_CHUNK];   // 16 KB
  __shared__ float    sAdj[BIN_CHUNK];    // 16 KB
  __shared__ ushort   sBkt[BIN_CHUNK];    //  8 KB
  __shared__ int      sCnt[1024];         //  4 KB
  __shared__ int      sScan[1024];        //  4 KB
  __shared__ int      sBase[1024];        //  4 KB
  __shared__ int      sFill[1024];        //  4 KB

  const int t = threadIdx.x;
  const int e0 = blockIdx.x * BIN_CHUNK;
  const int n = min(BIN_CHUNK, nedges - e0);

  sCnt[t] = 0;
  sBase[t] = 0;
  sFill[t] = 0;
  __syncthreads();

  int      eb[4];
  unsigned em[4];
  float    ea[4];
  #pragma unroll
  for (int j = 0; j < 4; ++j) {
    const int idx = t + j * BIN_BS;
    eb[j] = -1;
    if (idx < n) {
      const int r = row_idx[e0 + idx];
      const int c = col_idx[e0 + idx];
      ea[j] = adj[e0 + idx];
      eb[j] = r >> RPB_LOG;
      em[j] = ((unsigned)(r & (RPB - 1)) << 17) | (unsigned)c;
      atomicAdd(&sCnt[eb[j]], 1);
    }
  }
  __syncthreads();

  const int v = sCnt[t];
  sScan[t] = v;
  __syncthreads();
  int a = v;
  #pragma unroll
  for (int d = 1; d < 1024; d <<= 1) {
    const int add = (t >= d) ? sScan[t - d] : 0;
    __syncthreads();
    a += add;
    sScan[t] = a;
    __syncthreads();
  }
  const int excl = a - v;
  sScan[t] = excl;
  if (v > 0 && t < NB) sBase[t] = atomicAdd(&cursor[t], v);
  __syncthreads();

  #pragma unroll
  for (int j = 0; j < 4; ++j) {
    if (eb[j] >= 0) {
      const int p = sScan[eb[j]] + atomicAdd(&sFill[eb[j]], 1);
      sMeta[p] = em[j];
      sAdj[p] = ea[j];
      sBkt[p] = (ushort)eb[j];
    }
  }
  __syncthreads();

  #pragma unroll
  for (int j = 0; j < 4; ++j) {
    const int sp = t + j * BIN_BS;
    if (sp < n) {
      const int b = sBkt[sp];
      const int dst = sBase[b] + (sp - sScan[b]);
      int2 o;
      o.x = (int)sMeta[sp];
      o.y = __float_as_int(sAdj[sp]);
      packed[dst] = o;
    }
  }
}

// ---------------------------------------------------------------------------
// Kernel 5: bucket accumulate. Dual-row half-wave split (proven R15). Slab
// range: s = b*CAP, e = cursor[b] (final reservation watermark).
// ---------------------------------------------------------------------------
__global__ __launch_bounds__(ACC_BS) void bucket_acc_kernel(
    const int* __restrict__ cursor, const int2* __restrict__ packed,
    const ushort* __restrict__ hidden, float* __restrict__ out) {
  __shared__ float accT[RPB * OUT_F];    // 32 KB
  __shared__ int2  sEdge[ACC_CHUNK];     // 20 KB (meta, adj-bits)
  __shared__ int   rowCnt[RPB];
  __shared__ int   rowOff[RPB + 1];
  __shared__ int   sTmp[RPB];

  const int t = threadIdx.x;
  const int b = blockIdx.x;
  const int lane = t & 63;
  const int h  = lane >> 5;        // row-in-pair selector 0/1
  const int q  = (lane >> 4) & 1;  // edge parity within row
  const int fl = lane & 15;        // feat-quad index (feats 4fl..4fl+3)
  const int wv = t >> 6;           // 0..15

  const uint2* __restrict__ hid64 = (const uint2*)hidden; // [node][16]

  float4* a4 = (float4*)accT;
  #pragma unroll
  for (int i = 0; i < 2; ++i)
    a4[t + i * ACC_BS] = make_float4(0.f, 0.f, 0.f, 0.f);

  const int s = b * CAP;
  const int e = cursor[b];

  for (int g0 = s; g0 < e; g0 += ACC_CHUNK) {
    const int n = min(ACC_CHUNK, e - g0);

    if (t < RPB) rowCnt[t] = 0;
    __syncthreads();

    // load up to 3 edges/thread (coalesced), count rows (int LDS atomics)
    int2 ev[3];
    int  ro[3], pos[3];
    #pragma unroll
    for (int j = 0; j < 3; ++j) {
      const int idx = t + j * ACC_BS;
      ro[j] = -1;
      if (idx < n) {
        ev[j] = packed[g0 + idx];
        ro[j] = (int)(((unsigned)ev[j].x >> 17) & (RPB - 1));
        pos[j] = atomicAdd(&rowCnt[ro[j]], 1);
      }
    }
    __syncthreads();

    // block-wide exclusive scan of 128 row counts (proven)
    if (t < RPB) sTmp[t] = rowCnt[t];
    __syncthreads();
    for (int d = 1; d < RPB; d <<= 1) {
      int add = 0;
      if (t < RPB && t >= d) add = sTmp[t - d];
      __syncthreads();
      if (t < RPB) sTmp[t] += add;
      __syncthreads();
    }
    if (t < RPB) rowOff[t] = sTmp[t] - rowCnt[t];
    if (t == 0) rowOff[RPB] = n;
    __syncthreads();

    // scatter into row-sorted LDS positions (1 ds_write_b64 per edge)
    #pragma unroll
    for (int j = 0; j < 3; ++j) {
      if (ro[j] >= 0) sEdge[rowOff[ro[j]] + pos[j]] = ev[j];
    }
    __syncthreads();

    // accumulate: wave wv owns rows wv*8..wv*8+7 as 4 pairs; half-wave h
    // owns row 2*pr+h of each pair -> 2 independent gather chains per wave
    for (int pr = 0; pr < 4; ++pr) {
      const int r = wv * 8 + 2 * pr + h;
      const int rs = rowOff[r];
      const int re = rowOff[r + 1];
      float acc0 = 0.f, acc1 = 0.f, acc2 = 0.f, acc3 = 0.f;
      int i = rs + q;                 // this lane's edge stream: rs+q, +2, ...
      while (__any(i < re)) {
        const bool v0 = i < re;
        const bool v1 = i + 2 < re;
        const int2 e0 = sEdge[v0 ? i : 0];
        const int2 e1 = sEdge[v1 ? i + 2 : 0];
        const uint2 g0v = hid64[((unsigned)e0.x & 0x1FFFFu) * 16 + fl];
        const uint2 g1v = hid64[((unsigned)e1.x & 0x1FFFFu) * 16 + fl];
        const float a0 = v0 ? __int_as_float(e0.y) : 0.f;
        const float a1 = v1 ? __int_as_float(e1.y) : 0.f;
        acc0 = fmaf(a0, __uint_as_float(g0v.x << 16), acc0);
        acc1 = fmaf(a0, __uint_as_float(g0v.x & 0xFFFF0000u), acc1);
        acc2 = fmaf(a0, __uint_as_float(g0v.y << 16), acc2);
        acc3 = fmaf(a0, __uint_as_float(g0v.y & 0xFFFF0000u), acc3);
        acc0 = fmaf(a1, __uint_as_float(g1v.x << 16), acc0);
        acc1 = fmaf(a1, __uint_as_float(g1v.x & 0xFFFF0000u), acc1);
        acc2 = fmaf(a1, __uint_as_float(g1v.y << 16), acc2);
        acc3 = fmaf(a1, __uint_as_float(g1v.y & 0xFFFF0000u), acc3);
        i += 4;
      }
      // combine the two parities within this half (lane^16 flips q)
      acc0 += __shfl_xor(acc0, 16);
      acc1 += __shfl_xor(acc1, 16);
      acc2 += __shfl_xor(acc2, 16);
      acc3 += __shfl_xor(acc3, 16);
      if (q == 0) {
        float4* dst = (float4*)&accT[r * OUT_F + 4 * fl];
        float4 v = *dst;
        v.x += acc0; v.y += acc1; v.z += acc2; v.w += acc3;
        *dst = v;
      }
    }
    __syncthreads();  // chunk done before rowCnt/sEdge reuse
  }

  __syncthreads();
  const int rbase = b * RPB;
  float4* o4 = (float4*)(out + (size_t)rbase * OUT_F);
  #pragma unroll
  for (int i = 0; i < 2; ++i) {
    const int idx4 = t + i * ACC_BS;
    const int r = idx4 >> 4;  // 16 float4 per row
    if (rbase + r < N_NODES) {
      float4 vv = a4[idx4];
      vv.x = fmaxf(vv.x, 0.f);
      vv.y = fmaxf(vv.y, 0.f);
      vv.z = fmaxf(vv.z, 0.f);
      vv.w = fmaxf(vv.w, 0.f);
      o4[idx4] = vv;
    }
  }
}

extern "C" void kernel_launch(void* const* d_in, const int* in_sizes, int n_in,
                              void* d_out, int out_size, void* d_ws,
                              size_t ws_size, hipStream_t stream) {
  const float* x       = (const float*)d_in[0];
  const int*   row_idx = (const int*)d_in[1];
  const int*   col_idx = (const int*)d_in[2];
  const float* adj     = (const float*)d_in[3];
  const void*  mask    = d_in[4];
  const float* w       = (const float*)d_in[5];
  const float* bias    = (const float*)d_in[6];
  float* out = (float*)d_out;
  const int nedges = in_sizes[1];

  // ws layout (16B-aligned): hidden bf16 | cursor | packed slabs | Wt  (~32MB)
  char* ws = (char*)d_ws;
  const size_t off_hidden = 0;
  const size_t sz_hidden  = (size_t)N_NODES * OUT_F * sizeof(ushort);  // 12.8MB
  const size_t off_cursor = (off_hidden + sz_hidden + 15) & ~(size_t)15;
  const size_t off_packed = (off_cursor + 784 * 4 + 15) & ~(size_t)15;
  const size_t sz_packed  = (size_t)NB * CAP * 8;                      // 19.2MB
  const size_t off_wt     = (off_packed + sz_packed + 15) & ~(size_t)15;

  ushort* hidden = (ushort*)(ws + off_hidden);
  int*    cursor = (int*)(ws + off_cursor);
  int2*   packed = (int2*)(ws + off_packed);
  ushort* wt     = (ushort*)(ws + off_wt);

  wtrans_kernel<<<1, 256, 0, stream>>>(w, wt);
  gemm_dropout_kernel<<<(N_NODES + 63) / 64, 256, 0, stream>>>(
      x, wt, bias, mask, hidden, cursor);
  bin_kernel<<<(nedges + BIN_CHUNK - 1) / BIN_CHUNK, BIN_BS, 0, stream>>>(
      row_idx, col_idx, adj, cursor, packed, nedges);
  bucket_acc_kernel<<<NB, ACC_BS, 0, stream>>>(cursor, packed, hidden, out);
}

// Round 18
// 86.701 us; speedup vs baseline: 1.1998x; 1.0108x over previous
//
#include <hip/hip_runtime.h>
#include <hip/hip_bf16.h>

#define N_NODES 100000
#define IN_F    128
#define OUT_F   64
#define INV_KEEP (1.0f / 0.9f)

#define RPB_LOG 7                 // rows per bucket = 128
#define RPB (1 << RPB_LOG)
#define NB  ((N_NODES + RPB - 1) / RPB)   // 782 buckets
#define CAP 3072                  // fixed slab per bucket (mean 2048, +22 sigma)
#define BIN_CHUNK 4096
#define BIN_BS 1024
#define ACC_BS 1024
#define ACC_CHUNK 2560            // edges sorted per pass (avg bucket = 2046)

typedef __attribute__((ext_vector_type(8))) short bf16x8;
typedef __attribute__((ext_vector_type(4))) float f32x4;

__device__ __forceinline__ unsigned bf16rne(float f) {
  unsigned u = __float_as_uint(f);
  u += 0x7FFFu + ((u >> 16) & 1u);
  return u >> 16;
}

// ---------------------------------------------------------------------------
// Kernel 0: W [128][64] f32 -> Wt [64][128] bf16 (one block, runs once/call)
// ---------------------------------------------------------------------------
__global__ __launch_bounds__(256) void wtrans_kernel(
    const float* __restrict__ w, ushort* __restrict__ wt) {
  __shared__ float wsl[IN_F][OUT_F + 1];   // 128x65 f32, padded
  const int t = threadIdx.x;
  #pragma unroll
  for (int i = 0; i < 8; ++i) {
    const int fi = t + i * 256;            // float4 index
    const float4 v = ((const float4*)w)[fi];
    const int fl = 4 * fi;
    const int k = fl >> 6;
    const int c = fl & 63;
    wsl[k][c] = v.x; wsl[k][c + 1] = v.y; wsl[k][c + 2] = v.z; wsl[k][c + 3] = v.w;
  }
  __syncthreads();
  const int c = t >> 2;
  const int k0 = (t & 3) * 32;
  unsigned hw[16];
  #pragma unroll
  for (int i = 0; i < 16; ++i) {
    const unsigned u0 = bf16rne(wsl[k0 + 2 * i][c]);
    const unsigned u1 = bf16rne(wsl[k0 + 2 * i + 1][c]);
    hw[i] = u0 | (u1 << 16);               // low ushort = even k
  }
  uint4* dst = (uint4*)(wt + (size_t)c * IN_F + k0);
  dst[0] = make_uint4(hw[0], hw[1], hw[2], hw[3]);
  dst[1] = make_uint4(hw[4], hw[5], hw[6], hw[7]);
  dst[2] = make_uint4(hw[8], hw[9], hw[10], hw[11]);
  dst[3] = make_uint4(hw[12], hw[13], hw[14], hw[15]);
}

// ---------------------------------------------------------------------------
// Kernel 1: hidden = dropout(x @ W + b) -> bf16, via MFMA 16x16x32 bf16.
// Wave computes 16 rows x 64 cols; x split hi/lo bf16 (2 MFMA) for accuracy.
// Block 0 additionally initializes cursor[b] = b*CAP (slab bases).
// ---------------------------------------------------------------------------
__global__ __launch_bounds__(256) void gemm_dropout_kernel(
    const float* __restrict__ x, const ushort* __restrict__ wt,
    const float* __restrict__ bias, const void* __restrict__ mask,
    ushort* __restrict__ hidden, int* __restrict__ cursor) {
  __shared__ float tileT[64][68];          // 17.4 KB, 68-pad -> 2-way banks
  __shared__ int mask_is_u8;

  const int tid = threadIdx.x;
  const int wv = tid >> 6;                 // 0..3
  const int l = tid & 63;
  const int rowbase = blockIdx.x * 64;

  // fused: init per-bucket slab cursors (bin reserves from these)
  if (blockIdx.x == 0 && tid < 196) {
    const int c0 = 4 * tid;
    ((int4*)cursor)[tid] =
        make_int4(c0 * CAP, (c0 + 1) * CAP, (c0 + 2) * CAP, (c0 + 3) * CAP);
  }

  if (tid < 64) {
    const unsigned char* m8 = (const unsigned char*)mask;
    unsigned long long b = __ballot(m8[tid] != 0);
    if (tid == 0) mask_is_u8 = (__popcll(b) > 32) ? 1 : 0;
  }

  const int col = l & 15;
  const int kg = l >> 4;                   // 0..3

  int arow = rowbase + 16 * wv + col;
  if (arow >= N_NODES) arow = N_NODES - 1;
  const float* xrow = x + (size_t)arow * IN_F;

  // prefetch ALL x data first (8 independent loads in flight)
  float4 xa[4], xb[4];
  #pragma unroll
  for (int s = 0; s < 4; ++s) {
    xa[s] = *(const float4*)(xrow + 32 * s + 8 * kg);
    xb[s] = *(const float4*)(xrow + 32 * s + 8 * kg + 4);
  }

  // B fragments from Wt (16 KB, L2-resident; same for all blocks)
  bf16x8 bfr[4][4];                        // [col-tile][k-step]
  #pragma unroll
  for (int c = 0; c < 4; ++c)
    #pragma unroll
    for (int s = 0; s < 4; ++s)
      bfr[c][s] =
          *(const bf16x8*)(wt + (size_t)(16 * c + col) * IN_F + 32 * s + 8 * kg);

  f32x4 acc0 = {0.f, 0.f, 0.f, 0.f};
  f32x4 acc1 = {0.f, 0.f, 0.f, 0.f};
  f32x4 acc2 = {0.f, 0.f, 0.f, 0.f};
  f32x4 acc3 = {0.f, 0.f, 0.f, 0.f};

  #pragma unroll
  for (int s = 0; s < 4; ++s) {
    const float f[8] = {xa[s].x, xa[s].y, xa[s].z, xa[s].w,
                        xb[s].x, xb[s].y, xb[s].z, xb[s].w};
    bf16x8 ahi, alo;
    #pragma unroll
    for (int j = 0; j < 8; ++j) {
      const unsigned h = bf16rne(f[j]);
      ahi[j] = (short)h;
      const float lo = f[j] - __uint_as_float(h << 16);
      alo[j] = (short)bf16rne(lo);
    }
    acc0 = __builtin_amdgcn_mfma_f32_16x16x32_bf16(ahi, bfr[0][s], acc0, 0, 0, 0);
    acc1 = __builtin_amdgcn_mfma_f32_16x16x32_bf16(ahi, bfr[1][s], acc1, 0, 0, 0);
    acc2 = __builtin_amdgcn_mfma_f32_16x16x32_bf16(ahi, bfr[2][s], acc2, 0, 0, 0);
    acc3 = __builtin_amdgcn_mfma_f32_16x16x32_bf16(ahi, bfr[3][s], acc3, 0, 0, 0);
    acc0 = __builtin_amdgcn_mfma_f32_16x16x32_bf16(alo, bfr[0][s], acc0, 0, 0, 0);
    acc1 = __builtin_amdgcn_mfma_f32_16x16x32_bf16(alo, bfr[1][s], acc1, 0, 0, 0);
    acc2 = __builtin_amdgcn_mfma_f32_16x16x32_bf16(alo, bfr[2][s], acc2, 0, 0, 0);
    acc3 = __builtin_amdgcn_mfma_f32_16x16x32_bf16(alo, bfr[3][s], acc3, 0, 0, 0);
  }

  #pragma unroll
  for (int r = 0; r < 4; ++r) {
    const int lr = 16 * wv + 4 * kg + r;
    tileT[lr][0 + col]  = acc0[r];
    tileT[lr][16 + col] = acc1[r];
    tileT[lr][32 + col] = acc2[r];
    tileT[lr][48 + col] = acc3[r];
  }
  __syncthreads();

  const unsigned char* m8 = (const unsigned char*)mask;
  const int* m32 = (const int*)mask;
  const int u8mode = mask_is_u8;

  #pragma unroll
  for (int i = 0; i < 2; ++i) {
    const int item = tid + i * 256;
    const int r2 = item >> 3;              // 0..63
    const int cq = (item & 7) * 8;         // 0..56
    const int grow = rowbase + r2;
    if (grow < N_NODES) {
      const float4 b0 = *(const float4*)&bias[cq];
      const float4 b1 = *(const float4*)&bias[cq + 4];
      const float4 v0 = *(const float4*)&tileT[r2][cq];
      const float4 v1 = *(const float4*)&tileT[r2][cq + 4];
      const float vals[8] = {v0.x + b0.x, v0.y + b0.y, v0.z + b0.z, v0.w + b0.w,
                             v1.x + b1.x, v1.y + b1.y, v1.z + b1.z, v1.w + b1.w};
      unsigned keep[8];
      const size_t mbase = (size_t)grow * OUT_F + cq;
      if (u8mode) {
        const uint2 mv = *(const uint2*)(m8 + mbase);
        #pragma unroll
        for (int b = 0; b < 4; ++b) {
          keep[0 + b] = (mv.x >> (8 * b)) & 255u;
          keep[4 + b] = (mv.y >> (8 * b)) & 255u;
        }
      } else {
        const int4 mv0 = *(const int4*)(m32 + mbase);
        const int4 mv1 = *(const int4*)(m32 + mbase + 4);
        keep[0] = (unsigned)mv0.x; keep[1] = (unsigned)mv0.y;
        keep[2] = (unsigned)mv0.z; keep[3] = (unsigned)mv0.w;
        keep[4] = (unsigned)mv1.x; keep[5] = (unsigned)mv1.y;
        keep[6] = (unsigned)mv1.z; keep[7] = (unsigned)mv1.w;
      }
      unsigned hw[4];
      #pragma unroll
      for (int p = 0; p < 4; ++p) {
        const float w0 = keep[2 * p]     ? vals[2 * p] * INV_KEEP     : 0.f;
        const float w1 = keep[2 * p + 1] ? vals[2 * p + 1] * INV_KEEP : 0.f;
        hw[p] = bf16rne(w0) | (bf16rne(w1) << 16);
      }
      *(uint4*)&hidden[mbase] = make_uint4(hw[0], hw[1], hw[2], hw[3]);
    }
  }
}

// ---------------------------------------------------------------------------
// Kernel 4: bin — LDS counting-sort a 4096-edge chunk by bucket, then write
// coalesced runs into each bucket's FIXED SLAB. R18: hierarchical scan
// (wave shfl + 16-entry cross-wave) = 3 barriers instead of 20.
// ---------------------------------------------------------------------------
__global__ __launch_bounds__(BIN_BS) void bin_kernel(
    const int* __restrict__ row_idx, const int* __restrict__ col_idx,
    const float* __restrict__ adj, int* __restrict__ cursor,
    int2* __restrict__ packed, int nedges) {
  __shared__ unsigned sMeta[BIN_CHUNK];   // 16 KB
  __shared__ float    sAdj[BIN_CHUNK];    // 16 KB
  __shared__ ushort   sBkt[BIN_CHUNK];    //  8 KB
  __shared__ int      sCnt[1024];         //  4 KB
  __shared__ int      sScan[1024];        //  4 KB
  __shared__ int      sBase[1024];        //  4 KB
  __shared__ int      sFill[1024];        //  4 KB
  __shared__ int      sWSum[16];

  const int t = threadIdx.x;
  const int e0 = blockIdx.x * BIN_CHUNK;
  const int n = min(BIN_CHUNK, nedges - e0);
  const int wvi = t >> 6;
  const int ln = t & 63;

  sCnt[t] = 0;
  sBase[t] = 0;
  sFill[t] = 0;
  __syncthreads();

  int      eb[4];
  unsigned em[4];
  float    ea[4];
  #pragma unroll
  for (int j = 0; j < 4; ++j) {
    const int idx = t + j * BIN_BS;
    eb[j] = -1;
    if (idx < n) {
      const int r = row_idx[e0 + idx];
      const int c = col_idx[e0 + idx];
      ea[j] = adj[e0 + idx];
      eb[j] = r >> RPB_LOG;
      em[j] = ((unsigned)(r & (RPB - 1)) << 17) | (unsigned)c;
      atomicAdd(&sCnt[eb[j]], 1);
    }
  }
  __syncthreads();

  // hierarchical exclusive scan of sCnt[1024]: wave shfl + cross-wave
  const int v = sCnt[t];
  int sc = v;
  #pragma unroll
  for (int d = 1; d < 64; d <<= 1) {
    const int u = __shfl_up(sc, d);
    if (ln >= d) sc += u;
  }
  if (ln == 63) sWSum[wvi] = sc;           // wave totals
  __syncthreads();
  if (wvi == 0) {
    const int wval = (ln < 16) ? sWSum[ln] : 0;
    int wsc = wval;
    #pragma unroll
    for (int d = 1; d < 16; d <<= 1) {
      const int u = __shfl_up(wsc, d);
      if (ln >= d) wsc += u;
    }
    if (ln < 16) sWSum[ln] = wsc - wval;   // exclusive wave offsets
  }
  __syncthreads();
  const int excl = sc - v + sWSum[wvi];
  sScan[t] = excl;
  if (v > 0 && t < NB) sBase[t] = atomicAdd(&cursor[t], v);
  __syncthreads();

  #pragma unroll
  for (int j = 0; j < 4; ++j) {
    if (eb[j] >= 0) {
      const int p = sScan[eb[j]] + atomicAdd(&sFill[eb[j]], 1);
      sMeta[p] = em[j];
      sAdj[p] = ea[j];
      sBkt[p] = (ushort)eb[j];
    }
  }
  __syncthreads();

  #pragma unroll
  for (int j = 0; j < 4; ++j) {
    const int sp = t + j * BIN_BS;
    if (sp < n) {
      const int b = sBkt[sp];
      const int dst = sBase[b] + (sp - sScan[b]);
      int2 o;
      o.x = (int)sMeta[sp];
      o.y = __float_as_int(sAdj[sp]);
      packed[dst] = o;
    }
  }
}

// ---------------------------------------------------------------------------
// Kernel 5: bucket accumulate. Dual-row half-wave split (proven R15). Slab
// range: s = b*CAP, e = cursor[b] (final reservation watermark).
// ---------------------------------------------------------------------------
__global__ __launch_bounds__(ACC_BS) void bucket_acc_kernel(
    const int* __restrict__ cursor, const int2* __restrict__ packed,
    const ushort* __restrict__ hidden, float* __restrict__ out) {
  __shared__ float accT[RPB * OUT_F];    // 32 KB
  __shared__ int2  sEdge[ACC_CHUNK];     // 20 KB (meta, adj-bits)
  __shared__ int   rowCnt[RPB];
  __shared__ int   rowOff[RPB + 1];
  __shared__ int   sTmp[RPB];

  const int t = threadIdx.x;
  const int b = blockIdx.x;
  const int lane = t & 63;
  const int h  = lane >> 5;        // row-in-pair selector 0/1
  const int q  = (lane >> 4) & 1;  // edge parity within row
  const int fl = lane & 15;        // feat-quad index (feats 4fl..4fl+3)
  const int wv = t >> 6;           // 0..15

  const uint2* __restrict__ hid64 = (const uint2*)hidden; // [node][16]

  float4* a4 = (float4*)accT;
  #pragma unroll
  for (int i = 0; i < 2; ++i)
    a4[t + i * ACC_BS] = make_float4(0.f, 0.f, 0.f, 0.f);

  const int s = b * CAP;
  const int e = cursor[b];

  for (int g0 = s; g0 < e; g0 += ACC_CHUNK) {
    const int n = min(ACC_CHUNK, e - g0);

    if (t < RPB) rowCnt[t] = 0;
    __syncthreads();

    // load up to 3 edges/thread (coalesced), count rows (int LDS atomics)
    int2 ev[3];
    int  ro[3], pos[3];
    #pragma unroll
    for (int j = 0; j < 3; ++j) {
      const int idx = t + j * ACC_BS;
      ro[j] = -1;
      if (idx < n) {
        ev[j] = packed[g0 + idx];
        ro[j] = (int)(((unsigned)ev[j].x >> 17) & (RPB - 1));
        pos[j] = atomicAdd(&rowCnt[ro[j]], 1);
      }
    }
    __syncthreads();

    // block-wide exclusive scan of 128 row counts (proven)
    if (t < RPB) sTmp[t] = rowCnt[t];
    __syncthreads();
    for (int d = 1; d < RPB; d <<= 1) {
      int add = 0;
      if (t < RPB && t >= d) add = sTmp[t - d];
      __syncthreads();
      if (t < RPB) sTmp[t] += add;
      __syncthreads();
    }
    if (t < RPB) rowOff[t] = sTmp[t] - rowCnt[t];
    if (t == 0) rowOff[RPB] = n;
    __syncthreads();

    // scatter into row-sorted LDS positions (1 ds_write_b64 per edge)
    #pragma unroll
    for (int j = 0; j < 3; ++j) {
      if (ro[j] >= 0) sEdge[rowOff[ro[j]] + pos[j]] = ev[j];
    }
    __syncthreads();

    // accumulate: wave wv owns rows wv*8..wv*8+7 as 4 pairs; half-wave h
    // owns row 2*pr+h of each pair -> 2 independent gather chains per wave
    for (int pr = 0; pr < 4; ++pr) {
      const int r = wv * 8 + 2 * pr + h;
      const int rs = rowOff[r];
      const int re = rowOff[r + 1];
      float acc0 = 0.f, acc1 = 0.f, acc2 = 0.f, acc3 = 0.f;
      int i = rs + q;                 // this lane's edge stream: rs+q, +2, ...
      while (__any(i < re)) {
        const bool v0 = i < re;
        const bool v1 = i + 2 < re;
        const int2 e0 = sEdge[v0 ? i : 0];
        const int2 e1 = sEdge[v1 ? i + 2 : 0];
        const uint2 g0v = hid64[((unsigned)e0.x & 0x1FFFFu) * 16 + fl];
        const uint2 g1v = hid64[((unsigned)e1.x & 0x1FFFFu) * 16 + fl];
        const float a0 = v0 ? __int_as_float(e0.y) : 0.f;
        const float a1 = v1 ? __int_as_float(e1.y) : 0.f;
        acc0 = fmaf(a0, __uint_as_float(g0v.x << 16), acc0);
        acc1 = fmaf(a0, __uint_as_float(g0v.x & 0xFFFF0000u), acc1);
        acc2 = fmaf(a0, __uint_as_float(g0v.y << 16), acc2);
        acc3 = fmaf(a0, __uint_as_float(g0v.y & 0xFFFF0000u), acc3);
        acc0 = fmaf(a1, __uint_as_float(g1v.x << 16), acc0);
        acc1 = fmaf(a1, __uint_as_float(g1v.x & 0xFFFF0000u), acc1);
        acc2 = fmaf(a1, __uint_as_float(g1v.y << 16), acc2);
        acc3 = fmaf(a1, __uint_as_float(g1v.y & 0xFFFF0000u), acc3);
        i += 4;
      }
      // combine the two parities within this half (lane^16 flips q)
      acc0 += __shfl_xor(acc0, 16);
      acc1 += __shfl_xor(acc1, 16);
      acc2 += __shfl_xor(acc2, 16);
      acc3 += __shfl_xor(acc3, 16);
      if (q == 0) {
        float4* dst = (float4*)&accT[r * OUT_F + 4 * fl];
        float4 v = *dst;
        v.x += acc0; v.y += acc1; v.z += acc2; v.w += acc3;
        *dst = v;
      }
    }
    __syncthreads();  // chunk done before rowCnt/sEdge reuse
  }

  __syncthreads();
  const int rbase = b * RPB;
  float4* o4 = (float4*)(out + (size_t)rbase * OUT_F);
  #pragma unroll
  for (int i = 0; i < 2; ++i) {
    const int idx4 = t + i * ACC_BS;
    const int r = idx4 >> 4;  // 16 float4 per row
    if (rbase + r < N_NODES) {
      float4 vv = a4[idx4];
      vv.x = fmaxf(vv.x, 0.f);
      vv.y = fmaxf(vv.y, 0.f);
      vv.z = fmaxf(vv.z, 0.f);
      vv.w = fmaxf(vv.w, 0.f);
      o4[idx4] = vv;
    }
  }
}

extern "C" void kernel_launch(void* const* d_in, const int* in_sizes, int n_in,
                              void* d_out, int out_size, void* d_ws,
                              size_t ws_size, hipStream_t stream) {
  const float* x       = (const float*)d_in[0];
  const int*   row_idx = (const int*)d_in[1];
  const int*   col_idx = (const int*)d_in[2];
  const float* adj     = (const float*)d_in[3];
  const void*  mask    = d_in[4];
  const float* w       = (const float*)d_in[5];
  const float* bias    = (const float*)d_in[6];
  float* out = (float*)d_out;
  const int nedges = in_sizes[1];

  // ws layout (16B-aligned): hidden bf16 | cursor | packed slabs | Wt  (~32MB)
  char* ws = (char*)d_ws;
  const size_t off_hidden = 0;
  const size_t sz_hidden  = (size_t)N_NODES * OUT_F * sizeof(ushort);  // 12.8MB
  const size_t off_cursor = (off_hidden + sz_hidden + 15) & ~(size_t)15;
  const size_t off_packed = (off_cursor + 784 * 4 + 15) & ~(size_t)15;
  const size_t sz_packed  = (size_t)NB * CAP * 8;                      // 19.2MB
  const size_t off_wt     = (off_packed + sz_packed + 15) & ~(size_t)15;

  ushort* hidden = (ushort*)(ws + off_hidden);
  int*    cursor = (int*)(ws + off_cursor);
  int2*   packed = (int2*)(ws + off_packed);
  ushort* wt     = (ushort*)(ws + off_wt);

  wtrans_kernel<<<1, 256, 0, stream>>>(w, wt);
  gemm_dropout_kernel<<<(N_NODES + 63) / 64, 256, 0, stream>>>(
      x, wt, bias, mask, hidden, cursor);
  bin_kernel<<<(nedges + BIN_CHUNK - 1) / BIN_CHUNK, BIN_BS, 0, stream>>>(
      row_idx, col_idx, adj, cursor, packed, nedges);
  bucket_acc_kernel<<<NB, ACC_BS, 0, stream>>>(cursor, packed, hidden, out);
}